// Round 16
// baseline (73.445 us; speedup 1.0000x reference)
//
#include <hip/hip_runtime.h>
#include <hip/hip_bf16.h>

#define B_TOT  1024
#define IN_DIM 512
#define C_DIM  128
#define HID    128
#define EMB    32
#define BK     32
#define NKT    (IN_DIM / BK)   // 16

// workspace layout — operands FRAGMENT-PACKED (ushort idx):
#define WS_W1_STRIDE 65536ull
#define WS_W2_OFF    16777216ull
#define WS_X_OFF     17825792ull
#define WS_TMP_US    18350080ull                // ushort idx of bf16 tmp (byte 36,700,160)
#define WS_NEEDED1_B 36700160ull                // prepass + main
#define WS_NEEDED2_B 53477376ull                // + bf16 tmp (16.8 MB)

using bf16x8 = __attribute__((ext_vector_type(8))) short;
using f32x4  = __attribute__((ext_vector_type(4))) float;
using f32x2  = __attribute__((ext_vector_type(2))) float;

__device__ __forceinline__ unsigned short f2b(float f) {
    union { __hip_bfloat16 h; unsigned short u; } cv;
    cv.h = __float2bfloat16(f);
    return cv.u;
}
__device__ __forceinline__ float b2f32(unsigned short u) {
    union { unsigned int i; float f; } c;
    c.i = ((unsigned int)u) << 16;
    return c.f;
}
__device__ __forceinline__ unsigned int pack2(float a, float b) {
    return (unsigned int)f2b(a) | ((unsigned int)f2b(b) << 16);
}
__device__ __forceinline__ unsigned long long pack4(float a, float b, float c, float d) {
    return (unsigned long long)pack2(a, b) | ((unsigned long long)pack2(c, d) << 32);
}
__device__ __forceinline__ bf16x8 ld16(const unsigned short* p) {
    return *(const bf16x8*)p;
}
__device__ __forceinline__ void g2l16(const unsigned short* g, unsigned short* l) {
    __builtin_amdgcn_global_load_lds(
        (const __attribute__((address_space(1))) unsigned int*)(g),
        (__attribute__((address_space(3))) unsigned int*)(l), 16, 0, 0);
}

// ============================ prepass (unchanged) ============================
__global__ __launch_bounds__(256) void prepass(
    const float* __restrict__ x,
    const float* __restrict__ pW1, const float* __restrict__ pW2,
    const float* __restrict__ nW1, const float* __restrict__ nW2,
    unsigned short* __restrict__ ws)
{
    __shared__ unsigned short img[4096];
    const int blk     = blockIdx.x;
    const int pair    = blk >> 2;
    const int quarter = blk & 3;
    const int bank    = pair >> 7;
    const int c       = pair & 127;
    const int t       = threadIdx.x;

    const float* W1c = (bank ? nW1 : pW1) + (size_t)c * IN_DIM * HID;
    const float* W2c = (bank ? nW2 : pW2) + (size_t)c * HID * EMB;

    if (quarter == 0) {
        int e0 = (t & 7) * 4, h0 = (t >> 3) * 4;
        const float* src = &W2c[(size_t)h0 * EMB + e0];
        f32x4 L0 = *(const f32x4*)(src + 0 * EMB);
        f32x4 L1 = *(const f32x4*)(src + 1 * EMB);
        f32x4 L2 = *(const f32x4*)(src + 2 * EMB);
        f32x4 L3 = *(const f32x4*)(src + 3 * EMB);
        unsigned short* dst = ws + WS_W2_OFF + (size_t)pair * 4096;
#pragma unroll
        for (int j = 0; j < 4; ++j) {
            int e = e0 + j;
            int idx = (h0 >> 5) * 1024 + (e >> 4) * 512 +
                      ((((h0 & 31) >> 3) * 16 + (e & 15)) * 8) + (h0 & 7);
            *(unsigned long long*)&dst[idx] = pack4(L0[j], L1[j], L2[j], L3[j]);
        }
    }

#pragma unroll
    for (int q = 0; q < 4; ++q) {
        const int kt = quarter * 4 + q;
        const float* Wk = W1c + (size_t)kt * BK * HID;
        {
            int k0 = (t >> 5) * 4;
            int h0 = (t & 31) * 4;
            const float* src = &Wk[(size_t)k0 * HID + h0];
            f32x4 L0 = *(const f32x4*)(src + 0 * HID);
            f32x4 L1 = *(const f32x4*)(src + 1 * HID);
            f32x4 L2 = *(const f32x4*)(src + 2 * HID);
            f32x4 L3 = *(const f32x4*)(src + 3 * HID);
#pragma unroll
            for (int j = 0; j < 4; ++j) {
                int h = h0 + j;
                int idx = (h >> 4) * 512 +
                          (((k0 >> 3) * 16 + (h & 15)) * 8) + (k0 & 7);
                *(unsigned long long*)&img[idx] = pack4(L0[j], L1[j], L2[j], L3[j]);
            }
        }
        __syncthreads();
        unsigned short* dst = ws + (size_t)pair * WS_W1_STRIDE + (size_t)kt * 4096;
        *(bf16x8*)&dst[t * 16]     = *(const bf16x8*)&img[t * 16];
        *(bf16x8*)&dst[t * 16 + 8] = *(const bf16x8*)&img[t * 16 + 8];
        __syncthreads();
    }

    {
        const int row = blk;
        if (t < 128) {
            int k0 = t * 4;
            f32x4 v = *(const f32x4*)&x[(size_t)row * IN_DIM + k0];
            size_t idx = WS_X_OFF + (size_t)(row >> 7) * 65536 +
                         (size_t)(k0 >> 5) * 4096 + (size_t)((row & 127) >> 4) * 512 +
                         ((((k0 & 31) >> 3) * 16 + (row & 15)) * 8) + (k0 & 7);
            *(unsigned long long*)&ws[idx] = pack4(v[0], v[1], v[2], v[3]);
        }
    }
}

// ============================ main ============================
// r15 geometry + bf16 tmp; B operand (W1) moved OFF the LDS pipe: each wave
// loads its 8 B-frags/step straight global->VGPR (reg double-buffer, static
// indices). The 4 waves per wn read identical addresses -> L1 hits. LDS now
// carries only X (16KB write + 32KB read per step vs 128KB before).
__global__ __launch_bounds__(512, 2) void bank_main(
    const float* __restrict__ pb1, const float* __restrict__ pb2,
    const float* __restrict__ nb1, const float* __restrict__ nb2,
    const unsigned short* __restrict__ ws,
    unsigned short* __restrict__ tmp, // bf16 [pair][b][e]; nullptr -> scatter to out
    float* __restrict__ out)
{
    __shared__ unsigned short smem[32768];   // 64 KB (X dbuf in [0,16K); GEMM2 slots overlay)

    const int p     = blockIdx.x;          // 0..511
    const int xcd   = p & 7;
    const int rank  = p >> 3;              // 0..63
    const int cg    = rank & 7;
    const int btile = (rank >> 3) & 3;
    const int bank  = rank >> 5;
    const int c0    = xcd * 16 + cg * 2;
    const int bbase = btile * 256;

    const int t    = threadIdx.x;
    const int wave = t >> 6;
    const int lane = t & 63;
    const int lr   = lane & 15;
    const int lkg  = lane >> 4;
    const int wm   = wave >> 1;
    const int wn   = wave & 1;

    const unsigned short* xsrc0 = ws + WS_X_OFF + (size_t)(btile * 2) * 65536;
    const unsigned short* xsrc1 = xsrc0 + 65536;
    // per-wave B source (its channel), frag-packed; lane folded in
    const unsigned short* wsel  = ws + (size_t)(bank * 128 + c0 + wn) * WS_W1_STRIDE
                                  + lane * 8;

    f32x4 acc[4][8];
#pragma unroll
    for (int mi = 0; mi < 4; ++mi)
#pragma unroll
        for (int ni = 0; ni < 8; ++ni) acc[mi][ni] = (f32x4){0.f, 0.f, 0.f, 0.f};

#define STAGEX(KT, SEL)                                                         \
    {                                                                           \
        g2l16(xsrc0 + (KT) * 4096 + t * 8, &smem[(SEL) * 8192 + t * 8]);        \
        g2l16(xsrc1 + (KT) * 4096 + t * 8, &smem[(SEL) * 8192 + 4096 + t * 8]); \
    }

    bf16x8 B0[8], B1[8];

// Step KT: MFMA with BU (loaded during KT-1); prefetch BN for KT+1; X dbuf.
// __syncthreads at end drains vmcnt (B loads + X g2l for KT+1 complete).
#define KSTEP(KT, BU, BN, DOPRE)                                                \
    {                                                                           \
        if (DOPRE) {                                                            \
            _Pragma("unroll")                                                   \
            for (int n = 0; n < 8; ++n)                                         \
                BN[n] = ld16(wsel + ((KT) + 1) * 4096 + n * 512);               \
            STAGEX((KT) + 1, ((KT) + 1) & 1);                                   \
        }                                                                       \
        const unsigned short* Xb = &smem[((KT) & 1) * 8192 + (wm >> 1) * 4096 + \
                                         (wm & 1) * 2048 + lane * 8];           \
        bf16x8 af[4];                                                           \
        _Pragma("unroll")                                                       \
        for (int i = 0; i < 4; ++i) af[i] = ld16(Xb + i * 512);                 \
        __builtin_amdgcn_s_setprio(1);                                          \
        _Pragma("unroll")                                                       \
        for (int mi = 0; mi < 4; ++mi)                                          \
            _Pragma("unroll")                                                   \
            for (int ni = 0; ni < 8; ++ni)                                      \
                acc[mi][ni] = __builtin_amdgcn_mfma_f32_16x16x32_bf16(          \
                    af[mi], BU[ni], acc[mi][ni], 0, 0, 0);                      \
        __builtin_amdgcn_s_setprio(0);                                          \
        __syncthreads();                                                        \
    }

    // prologue: B(0) into B0, X(0) into buf 0
#pragma unroll
    for (int n = 0; n < 8; ++n) B0[n] = ld16(wsel + n * 512);
    STAGEX(0, 0);
    __syncthreads();

    KSTEP(0,  B0, B1, 1)  KSTEP(1,  B1, B0, 1)
    KSTEP(2,  B0, B1, 1)  KSTEP(3,  B1, B0, 1)
    KSTEP(4,  B0, B1, 1)  KSTEP(5,  B1, B0, 1)
    KSTEP(6,  B0, B1, 1)  KSTEP(7,  B1, B0, 1)
    KSTEP(8,  B0, B1, 1)  KSTEP(9,  B1, B0, 1)
    KSTEP(10, B0, B1, 1)  KSTEP(11, B1, B0, 1)
    KSTEP(12, B0, B1, 1)  KSTEP(13, B1, B0, 1)
    KSTEP(14, B0, B1, 1)  KSTEP(15, B1, B0, 0)
#undef KSTEP
#undef STAGEX

    const int cw   = c0 + wn;
    const int pw   = bank * 128 + cw;
    const float* b1c = (bank ? nb1 : pb1) + cw * HID;
    const float* b2c = (bank ? nb2 : pb2) + cw * EMB;
    float b1v[8];
#pragma unroll
    for (int ni = 0; ni < 8; ++ni) b1v[ni] = b1c[ni * 16 + lr];
    float b2v[2];
#pragma unroll
    for (int ei = 0; ei < 2; ++ei) b2v[ei] = b2c[ei * 16 + lr];

    const unsigned short* w2base = ws + WS_W2_OFF + (size_t)pw * 4096 + lane * 8;
    bf16x8 w2f[2][4];
#pragma unroll
    for (int k2 = 0; k2 < 4; ++k2)
#pragma unroll
        for (int ei = 0; ei < 2; ++ei)
            w2f[ei][k2] = ld16(w2base + k2 * 1024 + ei * 512);

    unsigned short* slot = &smem[wave * 4096];
    f32x4 acc2[4][2];
#pragma unroll
    for (int m2 = 0; m2 < 4; ++m2)
#pragma unroll
        for (int ei = 0; ei < 2; ++ei) acc2[m2][ei] = (f32x4){0.f, 0.f, 0.f, 0.f};

#pragma unroll
    for (int ch = 0; ch < 2; ++ch) {
#pragma unroll
        for (int mi = 0; mi < 4; ++mi) {
#pragma unroll
            for (int nq = 0; nq < 4; ++nq) {
                int ni = ch * 4 + nq;
                int lh = nq * 16 + lr;
#pragma unroll
                for (int j = 0; j < 4; ++j) {
                    int r = mi * 16 + lkg * 4 + j;
                    float v = fmaxf(acc[mi][ni][j] + b1v[ni], 0.f);
                    slot[r * 64 + ((((lh >> 3) & 7) ^ (r & 7)) << 3) + (lh & 7)] = f2b(v);
                }
            }
        }
#pragma unroll
        for (int kk = 0; kk < 2; ++kk) {
            int k2 = ch * 2 + kk;
            bf16x8 a2[4];
#pragma unroll
            for (int m2 = 0; m2 < 4; ++m2) {
                int r = m2 * 16 + lr;
                a2[m2] = ld16(&slot[r * 64 + (((kk * 4 + lkg) ^ (r & 7)) << 3)]);
            }
#pragma unroll
            for (int m2 = 0; m2 < 4; ++m2)
#pragma unroll
                for (int ei = 0; ei < 2; ++ei)
                    acc2[m2][ei] = __builtin_amdgcn_mfma_f32_16x16x32_bf16(
                        a2[m2], w2f[ei][k2], acc2[m2][ei], 0, 0, 0);
        }
    }

    if (tmp != nullptr) {
        unsigned short* tb = tmp + (size_t)pw * (B_TOT * EMB);
#pragma unroll
        for (int m2 = 0; m2 < 4; ++m2) {
#pragma unroll
            for (int ei = 0; ei < 2; ++ei) {
                int e = ei * 16 + lr;
#pragma unroll
                for (int j = 0; j < 4; ++j) {
                    int brow = bbase + wm * 64 + m2 * 16 + lkg * 4 + j;
                    tb[(size_t)brow * EMB + e] = f2b(acc2[m2][ei][j] + b2v[ei]);
                }
            }
        }
    } else {
        float* outb = out + (size_t)bank * B_TOT * EMB * C_DIM;
#pragma unroll
        for (int m2 = 0; m2 < 4; ++m2) {
#pragma unroll
            for (int ei = 0; ei < 2; ++ei) {
                int e = ei * 16 + lr;
#pragma unroll
                for (int j = 0; j < 4; ++j) {
                    int brow = bbase + wm * 64 + m2 * 16 + lkg * 4 + j;
                    outb[((size_t)brow * EMB + e) * C_DIM + cw] = acc2[m2][ei][j] + b2v[ei];
                }
            }
        }
    }
}

// ============================ untranspose (unchanged from r15) ==============
#define LP 1026
__global__ __launch_bounds__(256, 2) void untranspose(
    const unsigned short* __restrict__ tmp, float* __restrict__ out)
{
    __shared__ float lds[16 * LP];
    const int blk   = blockIdx.x;            // 0..511
    const int bank  = blk >> 8;
    const int cg    = (blk >> 5) & 7;
    const int chunk = blk & 31;
    const size_t beBase = (size_t)chunk * 1024;
    const int t = threadIdx.x;

#pragma unroll
    for (int ci = 0; ci < 16; ++ci) {
        const int pair = bank * 128 + cg * 16 + ci;
        unsigned long long q = *(const unsigned long long*)
            &tmp[(size_t)pair * (B_TOT * EMB) + beBase + t * 4];
#pragma unroll
        for (int j = 0; j < 4; ++j)
            lds[ci * LP + t * 4 + j] = b2f32((unsigned short)(q >> (16 * j)));
    }
    __syncthreads();

    float* outb = out + (size_t)bank * (B_TOT * EMB * C_DIM);
#pragma unroll
    for (int w = 0; w < 16; ++w) {
        int be = w * 64 + (t >> 2);
        int c4 = t & 3;
        f32x4 o;
#pragma unroll
        for (int j = 0; j < 4; ++j) o[j] = lds[(c4 * 4 + j) * LP + be];
        *(f32x4*)&outb[(beBase + be) * C_DIM + cg * 16 + c4 * 4] = o;
    }
}
#undef LP

// ===================== fallback (round-10 single kernel, known-good) ============
#define XS_LD 68
#define W1_LD 68
#define HS_LD 132
#define W2_LD 132
__device__ __forceinline__ bf16x8 load8u(const unsigned short* p) {
    union { unsigned long long q[2]; bf16x8 v; } u;
    u.q[0] = *(const unsigned long long*)(p);
    u.q[1] = *(const unsigned long long*)(p + 4);
    return u.v;
}
__global__ __launch_bounds__(256, 2) void bank_fallback(
    const float* __restrict__ x,
    const float* __restrict__ pW1, const float* __restrict__ pb1,
    const float* __restrict__ pW2, const float* __restrict__ pb2,
    const float* __restrict__ nW1, const float* __restrict__ nb1,
    const float* __restrict__ nW2, const float* __restrict__ nb2,
    float* __restrict__ out)
{
    __shared__ unsigned short Xs [128][XS_LD];
    __shared__ unsigned short W1T[HID][W1_LD];
    __shared__ unsigned short Hs [128][HS_LD];
    __shared__ unsigned short W2T[EMB][W2_LD];
    int p = blockIdx.x;
    int xcd = p & 7, rank = p >> 3;
    int c = xcd * 16 + (rank & 15);
    int btile = (rank >> 4) & 7;
    int bank = rank >> 7;
    int bbase = btile * 128;
    const float* W1c = (bank ? nW1 : pW1) + (size_t)c * IN_DIM * HID;
    const float* b1c = (bank ? nb1 : pb1) + c * HID;
    const float* W2c = (bank ? nW2 : pW2) + (size_t)c * HID * EMB;
    const float* b2c = (bank ? nb2 : pb2) + c * EMB;
    float* outb = out + (size_t)bank * B_TOT * EMB * C_DIM;
    int t = threadIdx.x, wave = t >> 6, lane = t & 63;
    int lr = lane & 15, lkg = lane >> 4, wm = wave >> 1, wn = wave & 1;
    {
        int e0 = (t & 7) * 4, h0 = (t >> 3) * 4;
        f32x4 L0 = *(const f32x4*)&W2c[(h0 + 0) * EMB + e0];
        f32x4 L1 = *(const f32x4*)&W2c[(h0 + 1) * EMB + e0];
        f32x4 L2 = *(const f32x4*)&W2c[(h0 + 2) * EMB + e0];
        f32x4 L3 = *(const f32x4*)&W2c[(h0 + 3) * EMB + e0];
#pragma unroll
        for (int j = 0; j < 4; ++j)
            *(unsigned long long*)&W2T[e0 + j][h0] = pack4(L0[j], L1[j], L2[j], L3[j]);
    }
    float b1v[4];
#pragma unroll
    for (int ni = 0; ni < 4; ++ni) b1v[ni] = b1c[wn * 64 + ni * 16 + lr];
    float b2v[2];
#pragma unroll
    for (int ei = 0; ei < 2; ++ei) b2v[ei] = b2c[ei * 16 + lr];
    f32x4 acc[4][4];
#pragma unroll
    for (int mi = 0; mi < 4; ++mi)
#pragma unroll
        for (int ni = 0; ni < 4; ++ni) acc[mi][ni] = (f32x4){0.f, 0.f, 0.f, 0.f};
    for (int kt = 0; kt < 8; ++kt) {
        int kb = kt * 64;
#pragma unroll
        for (int w8 = 0; w8 < 8; ++w8) {
            int f = w8 * 256 + t;
            int row = f >> 4, col = (f & 15) * 4;
            f32x4 v = *(const f32x4*)&x[(size_t)(bbase + row) * IN_DIM + kb + col];
            *(unsigned long long*)&Xs[row][col] = pack4(v[0], v[1], v[2], v[3]);
        }
#pragma unroll
        for (int g = 0; g < 2; ++g) {
            int s = g * 256 + t;
            int k0 = (s >> 5) * 4, h0 = (s & 31) * 4;
            const float* src = &W1c[(size_t)(kb + k0) * HID + h0];
            f32x4 L0 = *(const f32x4*)(src + 0 * HID);
            f32x4 L1 = *(const f32x4*)(src + 1 * HID);
            f32x4 L2 = *(const f32x4*)(src + 2 * HID);
            f32x4 L3 = *(const f32x4*)(src + 3 * HID);
#pragma unroll
            for (int j = 0; j < 4; ++j)
                *(unsigned long long*)&W1T[h0 + j][k0] = pack4(L0[j], L1[j], L2[j], L3[j]);
        }
        __syncthreads();
#pragma unroll
        for (int ki = 0; ki < 2; ++ki) {
            int kcol = ki * 32 + lkg * 8;
            bf16x8 af[4], bfr[4];
#pragma unroll
            for (int mi = 0; mi < 4; ++mi) af[mi] = load8u(&Xs[wm * 64 + mi * 16 + lr][kcol]);
#pragma unroll
            for (int ni = 0; ni < 4; ++ni) bfr[ni] = load8u(&W1T[wn * 64 + ni * 16 + lr][kcol]);
#pragma unroll
            for (int mi = 0; mi < 4; ++mi)
#pragma unroll
                for (int ni = 0; ni < 4; ++ni)
                    acc[mi][ni] = __builtin_amdgcn_mfma_f32_16x16x32_bf16(
                        af[mi], bfr[ni], acc[mi][ni], 0, 0, 0);
        }
        __syncthreads();
    }
#pragma unroll
    for (int mi = 0; mi < 4; ++mi) {
        int row = wm * 64 + mi * 16 + lkg * 4;
#pragma unroll
        for (int ni = 0; ni < 4; ++ni) {
            int col = wn * 64 + ni * 16 + lr;
#pragma unroll
            for (int j = 0; j < 4; ++j)
                Hs[row + j][col] = f2b(fmaxf(acc[mi][ni][j] + b1v[ni], 0.f));
        }
    }
    __syncthreads();
    f32x4 acc2[2][2];
#pragma unroll
    for (int m2 = 0; m2 < 2; ++m2)
#pragma unroll
        for (int ei = 0; ei < 2; ++ei) acc2[m2][ei] = (f32x4){0.f, 0.f, 0.f, 0.f};
    int rb = wave * 32;
#pragma unroll
    for (int k2 = 0; k2 < 4; ++k2) {
        int kcol = k2 * 32 + lkg * 8;
        bf16x8 a2[2], b2f[2];
#pragma unroll
        for (int m2 = 0; m2 < 2; ++m2) a2[m2] = load8u(&Hs[rb + m2 * 16 + lr][kcol]);
#pragma unroll
        for (int ei = 0; ei < 2; ++ei) b2f[ei] = load8u(&W2T[ei * 16 + lr][kcol]);
#pragma unroll
        for (int m2 = 0; m2 < 2; ++m2)
#pragma unroll
            for (int ei = 0; ei < 2; ++ei)
                acc2[m2][ei] = __builtin_amdgcn_mfma_f32_16x16x32_bf16(
                    a2[m2], b2f[ei], acc2[m2][ei], 0, 0, 0);
    }
#pragma unroll
    for (int m2 = 0; m2 < 2; ++m2)
#pragma unroll
        for (int ei = 0; ei < 2; ++ei) {
            int e = ei * 16 + lr;
#pragma unroll
            for (int j = 0; j < 4; ++j) {
                int brow = bbase + rb + m2 * 16 + lkg * 4 + j;
                outb[((size_t)brow * EMB + e) * C_DIM + c] = acc2[m2][ei][j] + b2v[ei];
            }
        }
}

extern "C" void kernel_launch(void* const* d_in, const int* in_sizes, int n_in,
                              void* d_out, int out_size, void* d_ws, size_t ws_size,
                              hipStream_t stream) {
    const float* x   = (const float*)d_in[0];
    const float* pW1 = (const float*)d_in[1];
    const float* pb1 = (const float*)d_in[2];
    const float* pW2 = (const float*)d_in[3];
    const float* pb2 = (const float*)d_in[4];
    const float* nW1 = (const float*)d_in[5];
    const float* nb1 = (const float*)d_in[6];
    const float* nW2 = (const float*)d_in[7];
    const float* nb2 = (const float*)d_in[8];
    float* out = (float*)d_out;

    if (ws_size >= WS_NEEDED2_B) {
        unsigned short* ws  = (unsigned short*)d_ws;
        unsigned short* tmp = (unsigned short*)d_ws + WS_TMP_US;
        prepass<<<dim3(1024), dim3(256), 0, stream>>>(x, pW1, pW2, nW1, nW2, ws);
        bank_main<<<dim3(512), dim3(512), 0, stream>>>(pb1, pb2, nb1, nb2, ws, tmp, out);
        untranspose<<<dim3(512), dim3(256), 0, stream>>>(tmp, out);
    } else if (ws_size >= WS_NEEDED1_B) {
        unsigned short* ws = (unsigned short*)d_ws;
        prepass<<<dim3(1024), dim3(256), 0, stream>>>(x, pW1, pW2, nW1, nW2, ws);
        bank_main<<<dim3(512), dim3(512), 0, stream>>>(pb1, pb2, nb1, nb2, ws,
                                                       (unsigned short*)nullptr, out);
    } else {
        bank_fallback<<<dim3(2048), dim3(256), 0, stream>>>(
            x, pW1, pb1, pW2, pb2, nW1, nb1, nW2, nb2, out);
    }
}

// Round 17
// 67.368 us; speedup vs baseline: 1.0902x; 1.0902x over previous
//
#include <hip/hip_runtime.h>
#include <hip/hip_bf16.h>

#define B_TOT  1024
#define IN_DIM 512
#define C_DIM  128
#define HID    128
#define EMB    32
#define BK     32
#define NKT    (IN_DIM / BK)   // 16

// workspace layout — operands FRAGMENT-PACKED (ushort idx):
#define WS_W1_STRIDE 65536ull
#define WS_W2_OFF    16777216ull
#define WS_X_OFF     17825792ull
#define WS_TMP_US    18350080ull                // ushort idx of bf16 tmp (byte 36,700,160)
#define WS_NEEDED1_B 36700160ull                // prepass + main
#define WS_NEEDED2_B 53477376ull                // + bf16 tmp (16.8 MB)

using bf16x8 = __attribute__((ext_vector_type(8))) short;
using f32x4  = __attribute__((ext_vector_type(4))) float;
using f32x2  = __attribute__((ext_vector_type(2))) float;

__device__ __forceinline__ unsigned short f2b(float f) {
    union { __hip_bfloat16 h; unsigned short u; } cv;
    cv.h = __float2bfloat16(f);
    return cv.u;
}
__device__ __forceinline__ float b2f32(unsigned short u) {
    union { unsigned int i; float f; } c;
    c.i = ((unsigned int)u) << 16;
    return c.f;
}
__device__ __forceinline__ unsigned int pack2(float a, float b) {
    return (unsigned int)f2b(a) | ((unsigned int)f2b(b) << 16);
}
__device__ __forceinline__ unsigned long long pack4(float a, float b, float c, float d) {
    return (unsigned long long)pack2(a, b) | ((unsigned long long)pack2(c, d) << 32);
}
__device__ __forceinline__ bf16x8 ld16(const unsigned short* p) {
    return *(const bf16x8*)p;
}
__device__ __forceinline__ void g2l16(const unsigned short* g, unsigned short* l) {
    __builtin_amdgcn_global_load_lds(
        (const __attribute__((address_space(1))) unsigned int*)(g),
        (__attribute__((address_space(3))) unsigned int*)(l), 16, 0, 0);
}

// ============================ prepass ============================
// 1024 blocks x 256 thr. Converts W1/W2/x to bf16 FRAGMENT-PACKED layouts in ws
// so bank_main's staging is pure linear global_load_lds + conflict-free ds_read.
__global__ __launch_bounds__(256) void prepass(
    const float* __restrict__ x,
    const float* __restrict__ pW1, const float* __restrict__ pW2,
    const float* __restrict__ nW1, const float* __restrict__ nW2,
    unsigned short* __restrict__ ws)
{
    __shared__ unsigned short img[4096];
    const int blk     = blockIdx.x;
    const int pair    = blk >> 2;
    const int quarter = blk & 3;
    const int bank    = pair >> 7;
    const int c       = pair & 127;
    const int t       = threadIdx.x;

    const float* W1c = (bank ? nW1 : pW1) + (size_t)c * IN_DIM * HID;
    const float* W2c = (bank ? nW2 : pW2) + (size_t)c * HID * EMB;

    if (quarter == 0) {
        int e0 = (t & 7) * 4, h0 = (t >> 3) * 4;
        const float* src = &W2c[(size_t)h0 * EMB + e0];
        f32x4 L0 = *(const f32x4*)(src + 0 * EMB);
        f32x4 L1 = *(const f32x4*)(src + 1 * EMB);
        f32x4 L2 = *(const f32x4*)(src + 2 * EMB);
        f32x4 L3 = *(const f32x4*)(src + 3 * EMB);
        unsigned short* dst = ws + WS_W2_OFF + (size_t)pair * 4096;
#pragma unroll
        for (int j = 0; j < 4; ++j) {
            int e = e0 + j;
            int idx = (h0 >> 5) * 1024 + (e >> 4) * 512 +
                      ((((h0 & 31) >> 3) * 16 + (e & 15)) * 8) + (h0 & 7);
            *(unsigned long long*)&dst[idx] = pack4(L0[j], L1[j], L2[j], L3[j]);
        }
    }

#pragma unroll
    for (int q = 0; q < 4; ++q) {
        const int kt = quarter * 4 + q;
        const float* Wk = W1c + (size_t)kt * BK * HID;
        {
            int k0 = (t >> 5) * 4;
            int h0 = (t & 31) * 4;
            const float* src = &Wk[(size_t)k0 * HID + h0];
            f32x4 L0 = *(const f32x4*)(src + 0 * HID);
            f32x4 L1 = *(const f32x4*)(src + 1 * HID);
            f32x4 L2 = *(const f32x4*)(src + 2 * HID);
            f32x4 L3 = *(const f32x4*)(src + 3 * HID);
#pragma unroll
            for (int j = 0; j < 4; ++j) {
                int h = h0 + j;
                int idx = (h >> 4) * 512 +
                          (((k0 >> 3) * 16 + (h & 15)) * 8) + (k0 & 7);
                *(unsigned long long*)&img[idx] = pack4(L0[j], L1[j], L2[j], L3[j]);
            }
        }
        __syncthreads();
        unsigned short* dst = ws + (size_t)pair * WS_W1_STRIDE + (size_t)kt * 4096;
        *(bf16x8*)&dst[t * 16]     = *(const bf16x8*)&img[t * 16];
        *(bf16x8*)&dst[t * 16 + 8] = *(const bf16x8*)&img[t * 16 + 8];
        __syncthreads();
    }

    {
        const int row = blk;
        if (t < 128) {
            int k0 = t * 4;
            f32x4 v = *(const f32x4*)&x[(size_t)row * IN_DIM + k0];
            size_t idx = WS_X_OFF + (size_t)(row >> 7) * 65536 +
                         (size_t)(k0 >> 5) * 4096 + (size_t)((row & 127) >> 4) * 512 +
                         ((((k0 & 31) >> 3) * 16 + (row & 15)) * 8) + (k0 & 7);
            *(unsigned long long*)&ws[idx] = pack4(v[0], v[1], v[2], v[3]);
        }
    }
}

// ============================ main (r15 keeper: 44.7 µs measured) ============
// 512 blocks x 512 thr (8 waves), 2 blocks/CU. Block = 256 B-rows x 2 channels.
// K-loop: frag-packed double-buffered LDS via linear global_load_lds (zero VALU
// staging, zero bank conflicts), 1 barrier/step. Wave-private GEMM2 epilogue.
// Stores CONTIGUOUS bf16 to tmp[pair][b][e] (the r13 scatter-store fix).
__global__ __launch_bounds__(512, 2) void bank_main(
    const float* __restrict__ pb1, const float* __restrict__ pb2,
    const float* __restrict__ nb1, const float* __restrict__ nb2,
    const unsigned short* __restrict__ ws,
    unsigned short* __restrict__ tmp, // bf16 [pair][b][e]; nullptr -> scatter to out
    float* __restrict__ out)
{
    __shared__ unsigned short smem[32768];   // 64 KB

    const int p     = blockIdx.x;          // 0..511
    const int xcd   = p & 7;
    const int rank  = p >> 3;              // 0..63
    const int cg    = rank & 7;
    const int btile = (rank >> 3) & 3;
    const int bank  = rank >> 5;
    const int c0    = xcd * 16 + cg * 2;
    const int bbase = btile * 256;

    const int t    = threadIdx.x;
    const int wave = t >> 6;
    const int lane = t & 63;
    const int lr   = lane & 15;
    const int lkg  = lane >> 4;
    const int wm   = wave >> 1;
    const int wn   = wave & 1;

    const unsigned short* xsrc0 = ws + WS_X_OFF + (size_t)(btile * 2) * 65536;
    const unsigned short* xsrc1 = xsrc0 + 65536;
    const unsigned short* wsrc0 = ws + (size_t)(bank * 128 + c0) * WS_W1_STRIDE;
    const unsigned short* wsrc1 = wsrc0 + WS_W1_STRIDE;

    f32x4 acc[4][8];
#pragma unroll
    for (int mi = 0; mi < 4; ++mi)
#pragma unroll
        for (int ni = 0; ni < 8; ++ni) acc[mi][ni] = (f32x4){0.f, 0.f, 0.f, 0.f};

#define STAGE(KT, SEL)                                                          \
    {                                                                           \
        g2l16(xsrc0 + (KT) * 4096 + t * 8, &smem[(SEL) * 8192 + t * 8]);        \
        g2l16(xsrc1 + (KT) * 4096 + t * 8, &smem[(SEL) * 8192 + 4096 + t * 8]); \
        g2l16(wsrc0 + (KT) * 4096 + t * 8, &smem[16384 + (SEL) * 8192 + t * 8]);\
        g2l16(wsrc1 + (KT) * 4096 + t * 8,                                      \
              &smem[16384 + (SEL) * 8192 + 4096 + t * 8]);                      \
    }

    STAGE(0, 0);
    __syncthreads();

    for (int kt = 0; kt < NKT; ++kt) {
        const int sel = kt & 1;
        if (kt < NKT - 1) STAGE(kt + 1, sel ^ 1);

        const unsigned short* Xb = &smem[sel * 8192 + (wm >> 1) * 4096 +
                                         (wm & 1) * 2048 + lane * 8];
        const unsigned short* Wb = &smem[16384 + sel * 8192 + wn * 4096 + lane * 8];
        bf16x8 af[4], bfr[8];
#pragma unroll
        for (int mi = 0; mi < 4; ++mi) af[mi] = ld16(Xb + mi * 512);
#pragma unroll
        for (int ni = 0; ni < 8; ++ni) bfr[ni] = ld16(Wb + ni * 512);

        __builtin_amdgcn_s_setprio(1);
#pragma unroll
        for (int mi = 0; mi < 4; ++mi)
#pragma unroll
            for (int ni = 0; ni < 8; ++ni)
                acc[mi][ni] = __builtin_amdgcn_mfma_f32_16x16x32_bf16(
                    af[mi], bfr[ni], acc[mi][ni], 0, 0, 0);
        __builtin_amdgcn_s_setprio(0);
        __syncthreads();
    }
#undef STAGE

    const int cw   = c0 + wn;
    const int pw   = bank * 128 + cw;
    const float* b1c = (bank ? nb1 : pb1) + cw * HID;
    const float* b2c = (bank ? nb2 : pb2) + cw * EMB;
    float b1v[8];
#pragma unroll
    for (int ni = 0; ni < 8; ++ni) b1v[ni] = b1c[ni * 16 + lr];
    float b2v[2];
#pragma unroll
    for (int ei = 0; ei < 2; ++ei) b2v[ei] = b2c[ei * 16 + lr];

    const unsigned short* w2base = ws + WS_W2_OFF + (size_t)pw * 4096 + lane * 8;
    bf16x8 w2f[2][4];
#pragma unroll
    for (int k2 = 0; k2 < 4; ++k2)
#pragma unroll
        for (int ei = 0; ei < 2; ++ei)
            w2f[ei][k2] = ld16(w2base + k2 * 1024 + ei * 512);

    unsigned short* slot = &smem[wave * 4096];
    f32x4 acc2[4][2];
#pragma unroll
    for (int m2 = 0; m2 < 4; ++m2)
#pragma unroll
        for (int ei = 0; ei < 2; ++ei) acc2[m2][ei] = (f32x4){0.f, 0.f, 0.f, 0.f};

#pragma unroll
    for (int ch = 0; ch < 2; ++ch) {
#pragma unroll
        for (int mi = 0; mi < 4; ++mi) {
#pragma unroll
            for (int nq = 0; nq < 4; ++nq) {
                int ni = ch * 4 + nq;
                int lh = nq * 16 + lr;
#pragma unroll
                for (int j = 0; j < 4; ++j) {
                    int r = mi * 16 + lkg * 4 + j;
                    float v = fmaxf(acc[mi][ni][j] + b1v[ni], 0.f);
                    slot[r * 64 + ((((lh >> 3) & 7) ^ (r & 7)) << 3) + (lh & 7)] = f2b(v);
                }
            }
        }
#pragma unroll
        for (int kk = 0; kk < 2; ++kk) {
            int k2 = ch * 2 + kk;
            bf16x8 a2[4];
#pragma unroll
            for (int m2 = 0; m2 < 4; ++m2) {
                int r = m2 * 16 + lr;
                a2[m2] = ld16(&slot[r * 64 + (((kk * 4 + lkg) ^ (r & 7)) << 3)]);
            }
#pragma unroll
            for (int m2 = 0; m2 < 4; ++m2)
#pragma unroll
                for (int ei = 0; ei < 2; ++ei)
                    acc2[m2][ei] = __builtin_amdgcn_mfma_f32_16x16x32_bf16(
                        a2[m2], w2f[ei][k2], acc2[m2][ei], 0, 0, 0);
        }
    }

    if (tmp != nullptr) {
        unsigned short* tb = tmp + (size_t)pw * (B_TOT * EMB);
#pragma unroll
        for (int m2 = 0; m2 < 4; ++m2) {
#pragma unroll
            for (int ei = 0; ei < 2; ++ei) {
                int e = ei * 16 + lr;
#pragma unroll
                for (int j = 0; j < 4; ++j) {
                    int brow = bbase + wm * 64 + m2 * 16 + lkg * 4 + j;
                    tb[(size_t)brow * EMB + e] = f2b(acc2[m2][ei][j] + b2v[ei]);
                }
            }
        }
    } else {
        float* outb = out + (size_t)bank * B_TOT * EMB * C_DIM;
#pragma unroll
        for (int m2 = 0; m2 < 4; ++m2) {
#pragma unroll
            for (int ei = 0; ei < 2; ++ei) {
                int e = ei * 16 + lr;
#pragma unroll
                for (int j = 0; j < 4; ++j) {
                    int brow = bbase + wm * 64 + m2 * 16 + lkg * 4 + j;
                    outb[((size_t)brow * EMB + e) * C_DIM + cw] = acc2[m2][ei][j] + b2v[ei];
                }
            }
        }
    }
}

// ============================ untranspose: bf16 tmp[pair][be] -> fp32 out[be][c] ====
#define LP 1026
__global__ __launch_bounds__(256, 2) void untranspose(
    const unsigned short* __restrict__ tmp, float* __restrict__ out)
{
    __shared__ float lds[16 * LP];
    const int blk   = blockIdx.x;            // 0..511
    const int bank  = blk >> 8;
    const int cg    = (blk >> 5) & 7;
    const int chunk = blk & 31;
    const size_t beBase = (size_t)chunk * 1024;
    const int t = threadIdx.x;

#pragma unroll
    for (int ci = 0; ci < 16; ++ci) {
        const int pair = bank * 128 + cg * 16 + ci;
        unsigned long long q = *(const unsigned long long*)
            &tmp[(size_t)pair * (B_TOT * EMB) + beBase + t * 4];
#pragma unroll
        for (int j = 0; j < 4; ++j)
            lds[ci * LP + t * 4 + j] = b2f32((unsigned short)(q >> (16 * j)));
    }
    __syncthreads();

    float* outb = out + (size_t)bank * (B_TOT * EMB * C_DIM);
#pragma unroll
    for (int w = 0; w < 16; ++w) {
        int be = w * 64 + (t >> 2);
        int c4 = t & 3;
        f32x4 o;
#pragma unroll
        for (int j = 0; j < 4; ++j) o[j] = lds[(c4 * 4 + j) * LP + be];
        *(f32x4*)&outb[(beBase + be) * C_DIM + cg * 16 + c4 * 4] = o;
    }
}
#undef LP

// ===================== fallback (round-10 single kernel, known-good) ============
#define XS_LD 68
#define W1_LD 68
#define HS_LD 132
#define W2_LD 132
__device__ __forceinline__ bf16x8 load8u(const unsigned short* p) {
    union { unsigned long long q[2]; bf16x8 v; } u;
    u.q[0] = *(const unsigned long long*)(p);
    u.q[1] = *(const unsigned long long*)(p + 4);
    return u.v;
}
__global__ __launch_bounds__(256, 2) void bank_fallback(
    const float* __restrict__ x,
    const float* __restrict__ pW1, const float* __restrict__ pb1,
    const float* __restrict__ pW2, const float* __restrict__ pb2,
    const float* __restrict__ nW1, const float* __restrict__ nb1,
    const float* __restrict__ nW2, const float* __restrict__ nb2,
    float* __restrict__ out)
{
    __shared__ unsigned short Xs [128][XS_LD];
    __shared__ unsigned short W1T[HID][W1_LD];
    __shared__ unsigned short Hs [128][HS_LD];
    __shared__ unsigned short W2T[EMB][W2_LD];
    int p = blockIdx.x;
    int xcd = p & 7, rank = p >> 3;
    int c = xcd * 16 + (rank & 15);
    int btile = (rank >> 4) & 7;
    int bank = rank >> 7;
    int bbase = btile * 128;
    const float* W1c = (bank ? nW1 : pW1) + (size_t)c * IN_DIM * HID;
    const float* b1c = (bank ? nb1 : pb1) + c * HID;
    const float* W2c = (bank ? nW2 : pW2) + (size_t)c * HID * EMB;
    const float* b2c = (bank ? nb2 : pb2) + c * EMB;
    float* outb = out + (size_t)bank * B_TOT * EMB * C_DIM;
    int t = threadIdx.x, wave = t >> 6, lane = t & 63;
    int lr = lane & 15, lkg = lane >> 4, wm = wave >> 1, wn = wave & 1;
    {
        int e0 = (t & 7) * 4, h0 = (t >> 3) * 4;
        f32x4 L0 = *(const f32x4*)&W2c[(h0 + 0) * EMB + e0];
        f32x4 L1 = *(const f32x4*)&W2c[(h0 + 1) * EMB + e0];
        f32x4 L2 = *(const f32x4*)&W2c[(h0 + 2) * EMB + e0];
        f32x4 L3 = *(const f32x4*)&W2c[(h0 + 3) * EMB + e0];
#pragma unroll
        for (int j = 0; j < 4; ++j)
            *(unsigned long long*)&W2T[e0 + j][h0] = pack4(L0[j], L1[j], L2[j], L3[j]);
    }
    float b1v[4];
#pragma unroll
    for (int ni = 0; ni < 4; ++ni) b1v[ni] = b1c[wn * 64 + ni * 16 + lr];
    float b2v[2];
#pragma unroll
    for (int ei = 0; ei < 2; ++ei) b2v[ei] = b2c[ei * 16 + lr];
    f32x4 acc[4][4];
#pragma unroll
    for (int mi = 0; mi < 4; ++mi)
#pragma unroll
        for (int ni = 0; ni < 4; ++ni) acc[mi][ni] = (f32x4){0.f, 0.f, 0.f, 0.f};
    for (int kt = 0; kt < 8; ++kt) {
        int kb = kt * 64;
#pragma unroll
        for (int w8 = 0; w8 < 8; ++w8) {
            int f = w8 * 256 + t;
            int row = f >> 4, col = (f & 15) * 4;
            f32x4 v = *(const f32x4*)&x[(size_t)(bbase + row) * IN_DIM + kb + col];
            *(unsigned long long*)&Xs[row][col] = pack4(v[0], v[1], v[2], v[3]);
        }
#pragma unroll
        for (int g = 0; g < 2; ++g) {
            int s = g * 256 + t;
            int k0 = (s >> 5) * 4, h0 = (s & 31) * 4;
            const float* src = &W1c[(size_t)(kb + k0) * HID + h0];
            f32x4 L0 = *(const f32x4*)(src + 0 * HID);
            f32x4 L1 = *(const f32x4*)(src + 1 * HID);
            f32x4 L2 = *(const f32x4*)(src + 2 * HID);
            f32x4 L3 = *(const f32x4*)(src + 3 * HID);
#pragma unroll
            for (int j = 0; j < 4; ++j)
                *(unsigned long long*)&W1T[h0 + j][k0] = pack4(L0[j], L1[j], L2[j], L3[j]);
        }
        __syncthreads();
#pragma unroll
        for (int ki = 0; ki < 2; ++ki) {
            int kcol = ki * 32 + lkg * 8;
            bf16x8 af[4], bfr[4];
#pragma unroll
            for (int mi = 0; mi < 4; ++mi) af[mi] = load8u(&Xs[wm * 64 + mi * 16 + lr][kcol]);
#pragma unroll
            for (int ni = 0; ni < 4; ++ni) bfr[ni] = load8u(&W1T[wn * 64 + ni * 16 + lr][kcol]);
#pragma unroll
            for (int mi = 0; mi < 4; ++mi)
#pragma unroll
                for (int ni = 0; ni < 4; ++ni)
                    acc[mi][ni] = __builtin_amdgcn_mfma_f32_16x16x32_bf16(
                        af[mi], bfr[ni], acc[mi][ni], 0, 0, 0);
        }
        __syncthreads();
    }
#pragma unroll
    for (int mi = 0; mi < 4; ++mi) {
        int row = wm * 64 + mi * 16 + lkg * 4;
#pragma unroll
        for (int ni = 0; ni < 4; ++ni) {
            int col = wn * 64 + ni * 16 + lr;
#pragma unroll
            for (int j = 0; j < 4; ++j)
                Hs[row + j][col] = f2b(fmaxf(acc[mi][ni][j] + b1v[ni], 0.f));
        }
    }
    __syncthreads();
    f32x4 acc2[2][2];
#pragma unroll
    for (int m2 = 0; m2 < 2; ++m2)
#pragma unroll
        for (int ei = 0; ei < 2; ++ei) acc2[m2][ei] = (f32x4){0.f, 0.f, 0.f, 0.f};
    int rb = wave * 32;
#pragma unroll
    for (int k2 = 0; k2 < 4; ++k2) {
        int kcol = k2 * 32 + lkg * 8;
        bf16x8 a2[2], b2f[2];
#pragma unroll
        for (int m2 = 0; m2 < 2; ++m2) a2[m2] = load8u(&Hs[rb + m2 * 16 + lr][kcol]);
#pragma unroll
        for (int ei = 0; ei < 2; ++ei) b2f[ei] = load8u(&W2T[ei * 16 + lr][kcol]);
#pragma unroll
        for (int m2 = 0; m2 < 2; ++m2)
#pragma unroll
            for (int ei = 0; ei < 2; ++ei)
                acc2[m2][ei] = __builtin_amdgcn_mfma_f32_16x16x32_bf16(
                    a2[m2], b2f[ei], acc2[m2][ei], 0, 0, 0);
    }
#pragma unroll
    for (int m2 = 0; m2 < 2; ++m2)
#pragma unroll
        for (int ei = 0; ei < 2; ++ei) {
            int e = ei * 16 + lr;
#pragma unroll
            for (int j = 0; j < 4; ++j) {
                int brow = bbase + rb + m2 * 16 + lkg * 4 + j;
                outb[((size_t)brow * EMB + e) * C_DIM + c] = acc2[m2][ei][j] + b2v[ei];
            }
        }
}

extern "C" void kernel_launch(void* const* d_in, const int* in_sizes, int n_in,
                              void* d_out, int out_size, void* d_ws, size_t ws_size,
                              hipStream_t stream) {
    const float* x   = (const float*)d_in[0];
    const float* pW1 = (const float*)d_in[1];
    const float* pb1 = (const float*)d_in[2];
    const float* pW2 = (const float*)d_in[3];
    const float* pb2 = (const float*)d_in[4];
    const float* nW1 = (const float*)d_in[5];
    const float* nb1 = (const float*)d_in[6];
    const float* nW2 = (const float*)d_in[7];
    const float* nb2 = (const float*)d_in[8];
    float* out = (float*)d_out;

    if (ws_size >= WS_NEEDED2_B) {
        unsigned short* ws  = (unsigned short*)d_ws;
        unsigned short* tmp = (unsigned short*)d_ws + WS_TMP_US;
        prepass<<<dim3(1024), dim3(256), 0, stream>>>(x, pW1, pW2, nW1, nW2, ws);
        bank_main<<<dim3(512), dim3(512), 0, stream>>>(pb1, pb2, nb1, nb2, ws, tmp, out);
        untranspose<<<dim3(512), dim3(256), 0, stream>>>(tmp, out);
    } else if (ws_size >= WS_NEEDED1_B) {
        unsigned short* ws = (unsigned short*)d_ws;
        prepass<<<dim3(1024), dim3(256), 0, stream>>>(x, pW1, pW2, nW1, nW2, ws);
        bank_main<<<dim3(512), dim3(512), 0, stream>>>(pb1, pb2, nb1, nb2, ws,
                                                       (unsigned short*)nullptr, out);
    } else {
        bank_fallback<<<dim3(2048), dim3(256), 0, stream>>>(
            x, pW1, pb1, pW2, pb2, nW1, nb1, nW2, nb2, out);
    }
}